// Round 18
// baseline (261.786 us; speedup 1.0000x reference)
//
#include <hip/hip_runtime.h>

typedef unsigned short u16;
typedef unsigned int u32;
typedef unsigned long long u64;
typedef __attribute__((ext_vector_type(8))) short bf16x8;
typedef __attribute__((ext_vector_type(4))) float f32x4;
typedef __attribute__((ext_vector_type(2))) unsigned int u32x2;

#define SEQ 2048
#define DM  768
#define NH  12
#define NB  2
#define LDQ (3 * DM)                    // 2304, row stride of fused qkv buffer

#define SCALE_Q 0.180336879f            // 0.125 * log2(e): folded into wq/bq
#define NEGB   -1.44269504e9f           // -1e9 * log2(e): mask value in exp2 domain

__device__ __forceinline__ float bf2f(u16 u) {
  union { u32 i; float f; } v; v.i = ((u32)u) << 16; return v.f;
}
__device__ __forceinline__ u16 f2bf(float f) {  // RNE (kernel outputs)
  union { float f; u32 i; } v; v.f = f;
  u32 r = v.i + 0x7FFFu + ((v.i >> 16) & 1u);
  return (u16)(r >> 16);
}
// raw HW exp2: 1 trans-pipe instr. Underflows big negatives (NEGB) to 0.
__device__ __forceinline__ float hw_exp2(float x) {
  float r;
  asm("v_exp_f32 %0, %1" : "=v"(r) : "v"(x));
  return r;
}
__device__ __forceinline__ void gl_lds16(const u16* g, u16* l) {
  __builtin_amdgcn_global_load_lds(
      (const __attribute__((address_space(1))) unsigned int*)g,
      (__attribute__((address_space(3))) unsigned int*)l, 16, 0, 0);
}
template<int N> __device__ __forceinline__ void wait_vmcnt() {
  if constexpr (N == 0) asm volatile("s_waitcnt vmcnt(0)" ::: "memory");
  else if constexpr (N == 2) asm volatile("s_waitcnt vmcnt(2)" ::: "memory");
  else if constexpr (N == 4) asm volatile("s_waitcnt vmcnt(4)" ::: "memory");
  else if constexpr (N == 5) asm volatile("s_waitcnt vmcnt(5)" ::: "memory");
}

// ------- merged prep: 6 weight transposes + bias concat + mask ballots --
__global__ __launch_bounds__(256) void prep_kernel(
    const float* __restrict__ wq, const float* __restrict__ wk,
    const float* __restrict__ wv, const float* __restrict__ wo,
    const float* __restrict__ w1, const float* __restrict__ w2,
    const float* __restrict__ bq, const float* __restrict__ bk,
    const float* __restrict__ bv, const int* __restrict__ mask,
    u16* __restrict__ wqkvt, u16* __restrict__ wot,
    u16* __restrict__ w1t, u16* __restrict__ w2t,
    float* __restrict__ bqkv, u64* __restrict__ mbitsT) {
  __shared__ float t[32][33];
  const int j = blockIdx.x, tid = threadIdx.x;
  const float* in = nullptr; u16* out = nullptr;
  int R = 0, C = 0, bx = 0, by = 0; float sc = 1.0f;
  if (j < 2304) {
    int which = j / 576, local = j % 576;
    in = which == 0 ? wq : which == 1 ? wk : which == 2 ? wv : wo;
    out = which == 3 ? wot : wqkvt + (size_t)which * DM * DM;
    sc = (which == 0) ? SCALE_Q : 1.0f;
    R = DM; C = DM; bx = local % 24; by = local / 24;
  } else if (j < 4608) {
    int local = j - 2304;
    in = w1; out = w1t; R = DM; C = 3072; bx = local % 96; by = local / 96;
  } else if (j < 6912) {
    int local = j - 4608;
    in = w2; out = w2t; R = 3072; C = DM; bx = local % 24; by = local / 24;
  } else if (j < 6921) {
    int i = (j - 6912) * 256 + tid;
    float v = (i < DM) ? bq[i] * SCALE_Q : (i < 2 * DM ? bk[i - DM] : bv[i - 2 * DM]);
    bqkv[i] = v;
    return;
  } else {
    int wid = (j - 6921) * 4 + (tid >> 6);      // (row, word)
    int lane = tid & 63;
    int row = wid >> 5, word = wid & 31;
    int m = mask[(long)row * SEQ + word * 64 + lane];
    u64 bb = __ballot(m != 0);
    if (lane == 0) mbitsT[(long)word * SEQ + row] = bb;  // transposed [32][2048]
    return;
  }
  long r0 = (long)by * 32, c0 = (long)bx * 32;
  int lc = tid & 31, wr = tid >> 5;
#pragma unroll
  for (int i = 0; i < 4; i++) {
    int row = wr + i * 8;
    t[row][lc] = in[(r0 + row) * C + c0 + lc];
  }
  __syncthreads();
#pragma unroll
  for (int i = 0; i < 4; i++) {
    int row = wr + i * 8;
    out[(c0 + row) * R + r0 + lc] = f2bf(t[lc][row] * sc);
  }
}

// ------- LayerNorm: fp32 in -> bf16 out (unbiased var, eps on std) -----
__global__ __launch_bounds__(256) void ln_kernel(
    const float* __restrict__ x, const float* __restrict__ alpha,
    const float* __restrict__ beta, u16* __restrict__ out) {
  long row = blockIdx.x;
  const float* xr = x + row * DM;
  int tid = threadIdx.x;
  float v[3];
  float s = 0.f, sq = 0.f;
#pragma unroll
  for (int i = 0; i < 3; i++) {
    v[i] = xr[tid + i * 256];
    s += v[i]; sq += v[i] * v[i];
  }
#pragma unroll
  for (int off = 32; off >= 1; off >>= 1) {
    s += __shfl_down(s, off, 64);
    sq += __shfl_down(sq, off, 64);
  }
  __shared__ float ss[4], ssq[4];
  int wave = tid >> 6;
  if ((tid & 63) == 0) { ss[wave] = s; ssq[wave] = sq; }
  __syncthreads();
  float ts = ss[0] + ss[1] + ss[2] + ss[3];
  float tsq = ssq[0] + ssq[1] + ssq[2] + ssq[3];
  float mean = ts * (1.0f / (float)DM);
  float var = fmaxf((tsq - ts * mean) * (1.0f / (float)(DM - 1)), 0.0f);
  float inv = 1.0f / (sqrtf(var) + 1e-6f);
#pragma unroll
  for (int i = 0; i < 3; i++) {
    int c = tid + i * 256;
    out[row * DM + c] = f2bf(alpha[c] * (v[i] - mean) * inv + beta[c]);
  }
}

// - GEMM: C[M,N] = A[M,Kld] @ Bt[N,Kld]^T + bias (+res) (+relu) ---------
// A staged via S=3 counted-vmcnt LDS pipeline (2 gl_lds/stage); B (weights,
// L1/L2-resident) read DIRECTLY global->register, prefetched 1 iter ahead.
// Issue order [.., stage(t+1), B(t+1), stage(t+2)] makes the steady
// vmcnt(2) drain exactly {stage(t), B(t)} while keeping prefetches flying.
// Halves DS-pipe traffic (the measured per-iteration bottleneck).
template<int BN>
__global__ __launch_bounds__(256, 3) void gemm_bt_kernel(
    const u16* __restrict__ A, const u16* __restrict__ Bt,
    const float* __restrict__ bias, const float* res,
    u16* Cb, float* Cf, u16* Vt, int vcol0, int M, int N, int K, int Kld,
    int relu, int nx, int wgPerChunk) {
  constexpr int NJ = BN / 32;
  __shared__ __align__(16) u16 As[3][128][32];   // 24 KB total
  const int tid = threadIdx.x;
  const int lane = tid & 63, wave = tid >> 6;
  const int g = lane >> 4, lr = lane & 15;
  const int wm = (wave >> 1) * 64, wn = (wave & 1) * (BN / 2);
  const int o = blockIdx.x;
  int wg = (o & 7) * ((int)gridDim.x >> 3) + (o >> 3);
  int chunk = 0;
  if (wgPerChunk) { chunk = wg / wgPerChunk; wg -= chunk * wgPerChunk; }
  const int bx = wg % nx, by = wg / nx;
  const long m0 = (long)by * 128;
  const long n0 = (long)bx * BN;
  const int srow = tid >> 2;
  const int scol = (tid & 3) * 8;
  const long koff = (long)chunk * K;

  const u16* aSrc = A + (m0 + srow) * Kld + koff + scol;
  // per-lane B fragment pointers (one per j), advanced by k0 at load time
  const u16* bp[NJ];
#pragma unroll
  for (int j = 0; j < NJ; j++)
    bp[j] = Bt + (n0 + wn + j * 16 + lr) * (long)Kld + koff + g * 8;

  auto STAGE = [&](int buf, int t) {
    const int k0 = t * 32;
    gl_lds16(aSrc + k0, &As[buf][srow][scol]);
    gl_lds16(aSrc + (long)64 * Kld + k0, &As[buf][srow + 64][scol]);
  };

  f32x4 acc[4][NJ];
#pragma unroll
  for (int i = 0; i < 4; i++)
#pragma unroll
    for (int j = 0; j < NJ; j++) acc[i][j] = (f32x4)0.0f;

  bf16x8 bcur[NJ], bnext[NJ];
  const int nk = K / 32;
  STAGE(0, 0);                                   // queue: [s0]
#pragma unroll
  for (int j = 0; j < NJ; j++) bcur[j] = *(const bf16x8*)(bp[j]);   // [s0,B0]
  STAGE(1, 1);                                   // [s0,B0,s1]
  for (int t = 0; t < nk; t++) {
    const int cur = t % 3;
    // steady: drains {stage(t), B(t)}, keeps stage(t+1) (2 newest) flying
    if (t + 1 < nk) wait_vmcnt<2>(); else wait_vmcnt<0>();
    __builtin_amdgcn_sched_barrier(0);
    __builtin_amdgcn_s_barrier();
    bf16x8 af[4];
#pragma unroll
    for (int i = 0; i < 4; i++) af[i] = *(const bf16x8*)&As[cur][wm + i * 16 + lr][g * 8];
#pragma unroll
    for (int i = 0; i < 4; i++)
#pragma unroll
      for (int j = 0; j < NJ; j++)
        acc[i][j] = __builtin_amdgcn_mfma_f32_16x16x32_bf16(af[i], bcur[j], acc[i][j], 0, 0, 0);
    if (t + 1 < nk) {
#pragma unroll
      for (int j = 0; j < NJ; j++) bnext[j] = *(const bf16x8*)(bp[j] + (t + 1) * 32);
    }
    __builtin_amdgcn_sched_barrier(0);           // pin: B(t+1) issues BEFORE stage(t+2)
    if (t + 2 < nk) STAGE((t + 2) % 3, t + 2);
#pragma unroll
    for (int j = 0; j < NJ; j++) bcur[j] = bnext[j];
  }
  const bool isV = (Vt != nullptr) && (n0 >= vcol0);   // block-uniform
#pragma unroll
  for (int j = 0; j < NJ; j++) {
    long col = n0 + wn + j * 16 + lr;
    float bv = (bias && chunk == 0) ? bias[col] : 0.0f;
#pragma unroll
    for (int i = 0; i < 4; i++) {
      float vals[4];
#pragma unroll
      for (int r = 0; r < 4; r++) {
        long row = m0 + wm + i * 16 + g * 4 + r;
        float v = acc[i][j][r] + bv;
        if (res && chunk == 0) v += res[row * N + col];
        if (relu) v = fmaxf(v, 0.0f);
        vals[r] = v;
        if (!isV) {
          if (wgPerChunk)  atomicAdd(&Cf[row * N + col], v);
          else if (Cb)     Cb[row * N + col] = f2bf(v);
          else             Cf[row * N + col] = v;
        }
      }
      if (isV) {
        // transposed V store: Vt[col - vcol0][row0..row0+3] as one 8B write
        long row0 = m0 + wm + i * 16 + g * 4;
        u32 lo = ((u32)f2bf(vals[1]) << 16) | f2bf(vals[0]);
        u32 hi = ((u32)f2bf(vals[3]) << 16) | f2bf(vals[2]);
        *(u32x2*)(Vt + (col - vcol0) * (long)(NB * SEQ) + row0) = (u32x2){lo, hi};
      }
    }
  }
}

// ------- flash attention: swapped QK^T, ONE barrier per KV tile --------
__global__ __launch_bounds__(256, 3) void attn_kernel(
    const u16* __restrict__ qkv, const u16* __restrict__ vt,
    const u64* __restrict__ mbitsT, u16* __restrict__ o_) {
  __shared__ __align__(16) u16 Ks[2][64][64];
  __shared__ __align__(16) u16 Vs[2][64][64];
  __shared__ __align__(16) u32 Ps32[4][16][36];
  const int o = blockIdx.x;
  const int wg = (o & 7) * 96 + (o >> 3);
  const int qt = wg & 31, h = (wg >> 5) % NH, b = wg / (32 * NH);
  const int tid = threadIdx.x;
  const int lane = tid & 63, wave = tid >> 6;
  const int g = lane >> 4, lr = lane & 15;
  const int qr0 = qt * 64 + wave * 16;
  const int NT = SEQ / 64;

  const u16* q = qkv;
  const u16* k = qkv + DM;

  const long qbase = ((long)(b * SEQ + qr0 + lr)) * LDQ + h * 64;
  bf16x8 qf0 = *(const bf16x8*)(q + qbase + g * 8);
  bf16x8 qf1 = *(const bf16x8*)(q + qbase + 32 + g * 8);

  bf16x8 onesf;
#pragma unroll
  for (int j = 0; j < 8; j++) onesf[j] = (short)0x3F80;

  f32x4 lsum = (f32x4)0.0f;
  f32x4 oacc[4];                               // O^T: row d=db*16+g*4+r, col q=lr
#pragma unroll
  for (int d = 0; d < 4; d++) oacc[d] = (f32x4)0.0f;

  const int strow = tid >> 3;
  const int stcolb = (tid & 7) * 16;
  const int swzb = stcolb ^ ((strow & 7) << 4);
  const u16* ksrc = k + (long)b * SEQ * LDQ + h * 64 + (swzb >> 1);
  const u16* vsrc = vt + ((long)(h * 64 + strow)) * (NB * SEQ) + (long)b * SEQ + (swzb >> 1);
  const int sc16 = stcolb >> 1;

  auto STAGE = [&](int buf, int kt) {
    const u16* kr = ksrc + (long)(kt * 64 + strow) * LDQ;
    gl_lds16(kr, &Ks[buf][strow][sc16]);
    gl_lds16(kr + (long)32 * LDQ, &Ks[buf][strow + 32][sc16]);
    const u16* vr = vsrc + kt * 64;
    gl_lds16(vr, &Vs[buf][strow][sc16]);
    gl_lds16(vr + 32 * (NB * SEQ), &Vs[buf][strow + 32][sc16]);
  };

  const int rs = (lr & 7) << 3;
  const int c0 = (g * 8) ^ rs;
  const int c1 = (32 + g * 8) ^ rs;

  const u64* mrow = mbitsT + (qr0 + lr);

  u64 mb_cur = mrow[0];
  STAGE(0, 0);
  for (int kt = 0; kt < NT; kt++) {
    const int cur = kt & 1;
    wait_vmcnt<0>();                           // own stage(t)+mask(t) drained
    __builtin_amdgcn_sched_barrier(0);
    __builtin_amdgcn_s_barrier();              // all compute(t-1) done; tile t valid
    u64 mb_new = 0;
    if (kt + 1 < NT) {
      mb_new = mrow[(long)(kt + 1) * SEQ];
      STAGE(cur ^ 1, kt + 1);                  // flies across this compute phase
    }

    f32x4 sf[4];
    __builtin_amdgcn_s_setprio(1);
#pragma unroll
    for (int n = 0; n < 4; n++) {
      bf16x8 kb0 = *(const bf16x8*)&Ks[cur][n * 16 + lr][c0];
      bf16x8 kb1 = *(const bf16x8*)&Ks[cur][n * 16 + lr][c1];
      sf[n] = __builtin_amdgcn_mfma_f32_16x16x32_bf16(kb0, qf0, (f32x4)0.0f, 0, 0, 0);
      sf[n] = __builtin_amdgcn_mfma_f32_16x16x32_bf16(kb1, qf1, sf[n], 0, 0, 0);
    }
    __builtin_amdgcn_s_setprio(0);
    u64 tsh = mb_cur >> (4 * g);
    u32 mlo = (u32)tsh, mhi = (u32)(tsh >> 32);
#pragma unroll
    for (int n = 0; n < 4; n++) {
      u32 w = (n < 2) ? mlo : mhi;
#pragma unroll
      for (int r = 0; r < 4; r++) {
        u32 bit = 1u << (16 * (n & 1) + r);
        sf[n][r] = (w & bit) ? sf[n][r] : NEGB;
      }
    }
    // P = exp2(s) via raw v_exp_f32 (1 instr); pack pairs via v_perm
#pragma unroll
    for (int n = 0; n < 4; n++) {
      union { float f; u32 i; } p0, p1, p2, p3;
      p0.f = hw_exp2(sf[n][0]); p1.f = hw_exp2(sf[n][1]);
      p2.f = hw_exp2(sf[n][2]); p3.f = hw_exp2(sf[n][3]);
      u32 w0 = __builtin_amdgcn_perm(p1.i, p0.i, 0x07060302u);
      u32 w1 = __builtin_amdgcn_perm(p3.i, p2.i, 0x07060302u);
      *(u32x2*)&Ps32[wave][lr][8 * n + 2 * g] = (u32x2){w0, w1};
    }
    asm volatile("" ::: "memory");             // order Ps writes vs reads (same wave)
    bf16x8 pf0 = *(const bf16x8*)&Ps32[wave][lr][4 * g];
    bf16x8 pf1 = *(const bf16x8*)&Ps32[wave][lr][16 + 4 * g];
    __builtin_amdgcn_s_setprio(1);
    lsum = __builtin_amdgcn_mfma_f32_16x16x32_bf16(onesf, pf0, lsum, 0, 0, 0);
    lsum = __builtin_amdgcn_mfma_f32_16x16x32_bf16(onesf, pf1, lsum, 0, 0, 0);
#pragma unroll
    for (int db = 0; db < 4; db++) {
      bf16x8 v0 = *(const bf16x8*)&Vs[cur][db * 16 + lr][c0];
      bf16x8 v1 = *(const bf16x8*)&Vs[cur][db * 16 + lr][c1];
      oacc[db] = __builtin_amdgcn_mfma_f32_16x16x32_bf16(v0, pf0, oacc[db], 0, 0, 0);
      oacc[db] = __builtin_amdgcn_mfma_f32_16x16x32_bf16(v1, pf1, oacc[db], 0, 0, 0);
    }
    __builtin_amdgcn_s_setprio(0);
    mb_cur = mb_new;
  }
  float inv = 1.0f / lsum[0];
  long row = (long)b * SEQ + qr0 + lr;
#pragma unroll
  for (int db = 0; db < 4; db++) {
    u32 lo = ((u32)f2bf(oacc[db][1] * inv) << 16) | f2bf(oacc[db][0] * inv);
    u32 hi = ((u32)f2bf(oacc[db][3] * inv) << 16) | f2bf(oacc[db][2] * inv);
    *(u32x2*)(o_ + row * DM + h * 64 + db * 16 + g * 4) = (u32x2){lo, hi};
  }
}

extern "C" void kernel_launch(void* const* d_in, const int* in_sizes, int n_in,
                              void* d_out, int out_size, void* d_ws, size_t ws_size,
                              hipStream_t stream) {
  const float* x      = (const float*)d_in[0];
  const int*   mask   = (const int*)d_in[1];
  const float* wq     = (const float*)d_in[2];
  const float* bq     = (const float*)d_in[3];
  const float* wk     = (const float*)d_in[4];
  const float* bk     = (const float*)d_in[5];
  const float* wv     = (const float*)d_in[6];
  const float* bv     = (const float*)d_in[7];
  const float* wo     = (const float*)d_in[8];
  const float* bo     = (const float*)d_in[9];
  const float* w1     = (const float*)d_in[10];
  const float* b1     = (const float*)d_in[11];
  const float* w2     = (const float*)d_in[12];
  const float* b2     = (const float*)d_in[13];
  const float* alpha1 = (const float*)d_in[14];
  const float* beta1  = (const float*)d_in[15];
  const float* alpha2 = (const float*)d_in[16];
  const float* beta2  = (const float*)d_in[17];
  float* outf = (float*)d_out;

  // ---- workspace layout (~52.6 MiB) ----
  char* ws = (char*)d_ws;
  size_t off = 0;
  auto alloc = [&](size_t bytes) {
    void* p = ws + off;
    off += (bytes + 255) & ~(size_t)255;
    return p;
  };
  const size_t DD = (size_t)DM * DM * 2;
  const size_t DF = (size_t)DM * 3072 * 2;
  const size_t ROWS = (size_t)NB * SEQ;
  const size_t ACT = ROWS * DM * 2;

  u16* wqkvt = (u16*)alloc(3 * DD);
  u16* wot   = (u16*)alloc(DD);
  u16* w1t   = (u16*)alloc(DF);
  u16* w2t   = (u16*)alloc(DF);
  float* bqkv = (float*)alloc(3 * DM * 4);
  u64* mbitsT = (u64*)alloc((size_t)(SEQ / 64) * SEQ * 8);  // [32][2048] 512KB
  u16* h     = (u16*)alloc(ACT);
  u16* qkv   = (u16*)alloc(ROWS * 3 * DM * 2);
  u16* vtb   = (u16*)alloc(ACT);
  u16* ob    = (u16*)alloc(ACT);
  u16* fb = qkv;           // [4096][3072] bf16 over dead qkv|vtb
  u16* h2 = h;
  float* x1 = outf;        // d_out doubles as x1

  dim3 blk(256);
  prep_kernel<<<dim3(23305), blk, 0, stream>>>(wq, wk, wv, wo, w1, w2, bq, bk, bv,
                                               mask, wqkvt, wot, w1t, w2t, bqkv, mbitsT);

  ln_kernel<<<ROWS, blk, 0, stream>>>(x, alpha1, beta1, h);
  // fused QKV; V-tiles (n0 >= 1536) written transposed straight into vtb
  gemm_bt_kernel<128><<<dim3(576), blk, 0, stream>>>(
      h, wqkvt, bqkv, nullptr, qkv, nullptr, vtb, 2 * DM, 4096, 3 * DM, 768, 768, 0, 18, 0);
  attn_kernel<<<dim3(32 * NH * NB), blk, 0, stream>>>(qkv, vtb, mbitsT, ob);
  gemm_bt_kernel<64><<<dim3(384), blk, 0, stream>>>(
      ob, wot, bo, x, nullptr, x1, nullptr, 0, 4096, 768, 768, 768, 0, 12, 0);
  ln_kernel<<<ROWS, blk, 0, stream>>>(x1, alpha2, beta2, h2);
  gemm_bt_kernel<128><<<dim3(768), blk, 0, stream>>>(
      h2, w1t, b1, nullptr, fb, nullptr, nullptr, 0, 4096, 3072, 768, 768, 1, 24, 0);
  // FFN2 split-K x2: out(x1, fp32) += chunk partials via atomicAdd
  gemm_bt_kernel<64><<<dim3(768), blk, 0, stream>>>(
      fb, w2t, b2, nullptr, nullptr, outf, nullptr, 0, 4096, 768, 1536, 3072, 0, 12, 384);
}

// Round 19
// 204.042 us; speedup vs baseline: 1.2830x; 1.2830x over previous
//
#include <hip/hip_runtime.h>

typedef unsigned short u16;
typedef unsigned int u32;
typedef unsigned long long u64;
typedef __attribute__((ext_vector_type(8))) short bf16x8;
typedef __attribute__((ext_vector_type(4))) float f32x4;
typedef __attribute__((ext_vector_type(2))) unsigned int u32x2;

#define SEQ 2048
#define DM  768
#define NH  12
#define NB  2
#define LDQ (3 * DM)                    // 2304, row stride of fused qkv buffer

#define SCALE_Q 0.180336879f            // 0.125 * log2(e): folded into wq/bq
#define NEGB   -1.44269504e9f           // -1e9 * log2(e): mask value in exp2 domain

__device__ __forceinline__ float bf2f(u16 u) {
  union { u32 i; float f; } v; v.i = ((u32)u) << 16; return v.f;
}
__device__ __forceinline__ u16 f2bf(float f) {  // RNE (kernel outputs)
  union { float f; u32 i; } v; v.f = f;
  u32 r = v.i + 0x7FFFu + ((v.i >> 16) & 1u);
  return (u16)(r >> 16);
}
// raw HW exp2: 1 trans-pipe instr. Underflows big negatives (NEGB) to 0.
__device__ __forceinline__ float hw_exp2(float x) {
  float r;
  asm("v_exp_f32 %0, %1" : "=v"(r) : "v"(x));
  return r;
}
__device__ __forceinline__ void gl_lds16(const u16* g, u16* l) {
  __builtin_amdgcn_global_load_lds(
      (const __attribute__((address_space(1))) unsigned int*)g,
      (__attribute__((address_space(3))) unsigned int*)l, 16, 0, 0);
}
template<int N> __device__ __forceinline__ void wait_vmcnt() {
  if constexpr (N == 0) asm volatile("s_waitcnt vmcnt(0)" ::: "memory");
  else if constexpr (N == 3) asm volatile("s_waitcnt vmcnt(3)" ::: "memory");
  else if constexpr (N == 4) asm volatile("s_waitcnt vmcnt(4)" ::: "memory");
  else if constexpr (N == 5) asm volatile("s_waitcnt vmcnt(5)" ::: "memory");
}

// ------- merged prep: 6 weight transposes + bias concat + mask ballots --
__global__ __launch_bounds__(256) void prep_kernel(
    const float* __restrict__ wq, const float* __restrict__ wk,
    const float* __restrict__ wv, const float* __restrict__ wo,
    const float* __restrict__ w1, const float* __restrict__ w2,
    const float* __restrict__ bq, const float* __restrict__ bk,
    const float* __restrict__ bv, const int* __restrict__ mask,
    u16* __restrict__ wqkvt, u16* __restrict__ wot,
    u16* __restrict__ w1t, u16* __restrict__ w2t,
    float* __restrict__ bqkv, u64* __restrict__ mbitsT) {
  __shared__ float t[32][33];
  const int j = blockIdx.x, tid = threadIdx.x;
  const float* in = nullptr; u16* out = nullptr;
  int R = 0, C = 0, bx = 0, by = 0; float sc = 1.0f;
  if (j < 2304) {
    int which = j / 576, local = j % 576;
    in = which == 0 ? wq : which == 1 ? wk : which == 2 ? wv : wo;
    out = which == 3 ? wot : wqkvt + (size_t)which * DM * DM;
    sc = (which == 0) ? SCALE_Q : 1.0f;
    R = DM; C = DM; bx = local % 24; by = local / 24;
  } else if (j < 4608) {
    int local = j - 2304;
    in = w1; out = w1t; R = DM; C = 3072; bx = local % 96; by = local / 96;
  } else if (j < 6912) {
    int local = j - 4608;
    in = w2; out = w2t; R = 3072; C = DM; bx = local % 24; by = local / 24;
  } else if (j < 6921) {
    int i = (j - 6912) * 256 + tid;
    float v = (i < DM) ? bq[i] * SCALE_Q : (i < 2 * DM ? bk[i - DM] : bv[i - 2 * DM]);
    bqkv[i] = v;
    return;
  } else {
    int wid = (j - 6921) * 4 + (tid >> 6);      // (row, word)
    int lane = tid & 63;
    int row = wid >> 5, word = wid & 31;
    int m = mask[(long)row * SEQ + word * 64 + lane];
    u64 bb = __ballot(m != 0);
    if (lane == 0) mbitsT[(long)word * SEQ + row] = bb;  // transposed [32][2048]
    return;
  }
  long r0 = (long)by * 32, c0 = (long)bx * 32;
  int lc = tid & 31, wr = tid >> 5;
#pragma unroll
  for (int i = 0; i < 4; i++) {
    int row = wr + i * 8;
    t[row][lc] = in[(r0 + row) * C + c0 + lc];
  }
  __syncthreads();
#pragma unroll
  for (int i = 0; i < 4; i++) {
    int row = wr + i * 8;
    out[(c0 + row) * R + r0 + lc] = f2bf(t[lc][row] * sc);
  }
}

// ------- LayerNorm: fp32 in -> bf16 out (unbiased var, eps on std) -----
__global__ __launch_bounds__(256) void ln_kernel(
    const float* __restrict__ x, const float* __restrict__ alpha,
    const float* __restrict__ beta, u16* __restrict__ out) {
  long row = blockIdx.x;
  const float* xr = x + row * DM;
  int tid = threadIdx.x;
  float v[3];
  float s = 0.f, sq = 0.f;
#pragma unroll
  for (int i = 0; i < 3; i++) {
    v[i] = xr[tid + i * 256];
    s += v[i]; sq += v[i] * v[i];
  }
#pragma unroll
  for (int off = 32; off >= 1; off >>= 1) {
    s += __shfl_down(s, off, 64);
    sq += __shfl_down(sq, off, 64);
  }
  __shared__ float ss[4], ssq[4];
  int wave = tid >> 6;
  if ((tid & 63) == 0) { ss[wave] = s; ssq[wave] = sq; }
  __syncthreads();
  float ts = ss[0] + ss[1] + ss[2] + ss[3];
  float tsq = ssq[0] + ssq[1] + ssq[2] + ssq[3];
  float mean = ts * (1.0f / (float)DM);
  float var = fmaxf((tsq - ts * mean) * (1.0f / (float)(DM - 1)), 0.0f);
  float inv = 1.0f / (sqrtf(var) + 1e-6f);
#pragma unroll
  for (int i = 0; i < 3; i++) {
    int c = tid + i * 256;
    out[row * DM + c] = f2bf(alpha[c] * (v[i] - mean) * inv + beta[c]);
  }
}

// - GEMM: C[M,N] = A[M,Kld] @ Bt[N,Kld]^T + bias (+res) (+relu) ---------
// S=3 counted-vmcnt pipeline (T4), 1D grid + XCD swizzle (T1).
// Split-K (wgPerChunk>0): 2 chunks, fp32 atomicAdd into Cf (chunk0 adds bias).
// Vt != nullptr: n-tiles with n0 >= vcol0 write TRANSPOSED to Vt[col-vcol0][row]
// (4 consecutive rows packed per 8B store) instead of Cb -- fuses V transpose.
template<int BN>
__global__ __launch_bounds__(256, 2) void gemm_bt_kernel(
    const u16* __restrict__ A, const u16* __restrict__ Bt,
    const float* __restrict__ bias, const float* res,
    u16* Cb, float* Cf, u16* Vt, int vcol0, int M, int N, int K, int Kld,
    int relu, int nx, int wgPerChunk) {
  constexpr int NJ = BN / 32;
  constexpr int L = (BN == 128) ? 4 : 3;      // gl_lds ops per STAGE
  __shared__ __align__(16) u16 As[3][128][32];
  __shared__ __align__(16) u16 Bs[3][BN][32];
  const int tid = threadIdx.x;
  const int lane = tid & 63, wave = tid >> 6;
  const int g = lane >> 4, lr = lane & 15;
  const int wm = (wave >> 1) * 64, wn = (wave & 1) * (BN / 2);
  const int o = blockIdx.x;
  int wg = (o & 7) * ((int)gridDim.x >> 3) + (o >> 3);
  int chunk = 0;
  if (wgPerChunk) { chunk = wg / wgPerChunk; wg -= chunk * wgPerChunk; }
  const int bx = wg % nx, by = wg / nx;
  const long m0 = (long)by * 128;
  const long n0 = (long)bx * BN;
  const int srow = tid >> 2;
  const int scol = (tid & 3) * 8;
  const long koff = (long)chunk * K;

  const u16* aSrc = A + (m0 + srow) * Kld + koff + scol;
  const u16* bSrc = Bt + (n0 + srow) * Kld + koff + scol;

  auto STAGE = [&](int buf, int t) {
    const int k0 = t * 32;
    gl_lds16(aSrc + k0, &As[buf][srow][scol]);
    gl_lds16(aSrc + (long)64 * Kld + k0, &As[buf][srow + 64][scol]);
    gl_lds16(bSrc + k0, &Bs[buf][srow][scol]);
    if (BN == 128) gl_lds16(bSrc + (long)64 * Kld + k0, &Bs[buf][srow + 64][scol]);
  };

  f32x4 acc[4][NJ];
#pragma unroll
  for (int i = 0; i < 4; i++)
#pragma unroll
    for (int j = 0; j < NJ; j++) acc[i][j] = (f32x4)0.0f;

  const int nk = K / 32;
  STAGE(0, 0);
  STAGE(1, 1);
  for (int t = 0; t < nk; t++) {
    const int cur = t % 3;
    if (t + 1 < nk) wait_vmcnt<L>(); else wait_vmcnt<0>();
    __builtin_amdgcn_sched_barrier(0);
    __builtin_amdgcn_s_barrier();
    bf16x8 af[4], bfr[NJ];
#pragma unroll
    for (int i = 0; i < 4; i++) af[i] = *(const bf16x8*)&As[cur][wm + i * 16 + lr][g * 8];
#pragma unroll
    for (int j = 0; j < NJ; j++) bfr[j] = *(const bf16x8*)&Bs[cur][wn + j * 16 + lr][g * 8];
#pragma unroll
    for (int i = 0; i < 4; i++)
#pragma unroll
      for (int j = 0; j < NJ; j++)
        acc[i][j] = __builtin_amdgcn_mfma_f32_16x16x32_bf16(af[i], bfr[j], acc[i][j], 0, 0, 0);
    if (t + 2 < nk) STAGE((t + 2) % 3, t + 2);
  }
  const bool isV = (Vt != nullptr) && (n0 >= vcol0);   // block-uniform
#pragma unroll
  for (int j = 0; j < NJ; j++) {
    long col = n0 + wn + j * 16 + lr;
    float bv = (bias && chunk == 0) ? bias[col] : 0.0f;
#pragma unroll
    for (int i = 0; i < 4; i++) {
      float vals[4];
#pragma unroll
      for (int r = 0; r < 4; r++) {
        long row = m0 + wm + i * 16 + g * 4 + r;
        float v = acc[i][j][r] + bv;
        if (res) v += res[row * N + col];
        if (relu) v = fmaxf(v, 0.0f);
        vals[r] = v;
        if (!isV) {
          if (wgPerChunk)  atomicAdd(&Cf[row * N + col], v);
          else if (Cb)     Cb[row * N + col] = f2bf(v);
          else             Cf[row * N + col] = v;
        }
      }
      if (isV) {
        // transposed V store: Vt[col - vcol0][row0..row0+3] as one 8B write
        long row0 = m0 + wm + i * 16 + g * 4;
        u32 lo = ((u32)f2bf(vals[1]) << 16) | f2bf(vals[0]);
        u32 hi = ((u32)f2bf(vals[3]) << 16) | f2bf(vals[2]);
        *(u32x2*)(Vt + (col - vcol0) * (long)(NB * SEQ) + row0) = (u32x2){lo, hi};
      }
    }
  }
}

// ------- flash attention: swapped QK^T, ONE barrier per KV tile --------
// 1D grid 768, XCD-chunked swizzle. Order per iter:
//   vmcnt(0) [drains own stage(t)+mask(t), issued a full compute ago]
//   barrier  [=> ALL waves finished compute(t-1); all stage(t) visible]
//   issue mask(t+1)+STAGE(t+1) [flies across the whole compute phase]
//   compute(t)
// Safe: a wave passing barrier t implies it finished compute(t-1), so
// STAGE(t+1)'s overwrite of buf[(t-1)&1] cannot race any reader.
__global__ __launch_bounds__(256, 3) void attn_kernel(
    const u16* __restrict__ qkv, const u16* __restrict__ vt,
    const u64* __restrict__ mbitsT, u16* __restrict__ o_) {
  __shared__ __align__(16) u16 Ks[2][64][64];
  __shared__ __align__(16) u16 Vs[2][64][64];
  __shared__ __align__(16) u32 Ps32[4][16][36];
  const int o = blockIdx.x;
  const int wg = (o & 7) * 96 + (o >> 3);
  const int qt = wg & 31, h = (wg >> 5) % NH, b = wg / (32 * NH);
  const int tid = threadIdx.x;
  const int lane = tid & 63, wave = tid >> 6;
  const int g = lane >> 4, lr = lane & 15;
  const int qr0 = qt * 64 + wave * 16;
  const int NT = SEQ / 64;

  const u16* q = qkv;
  const u16* k = qkv + DM;

  const long qbase = ((long)(b * SEQ + qr0 + lr)) * LDQ + h * 64;
  bf16x8 qf0 = *(const bf16x8*)(q + qbase + g * 8);
  bf16x8 qf1 = *(const bf16x8*)(q + qbase + 32 + g * 8);

  bf16x8 onesf;
#pragma unroll
  for (int j = 0; j < 8; j++) onesf[j] = (short)0x3F80;

  f32x4 lsum = (f32x4)0.0f;
  f32x4 oacc[4];                               // O^T: row d=db*16+g*4+r, col q=lr
#pragma unroll
  for (int d = 0; d < 4; d++) oacc[d] = (f32x4)0.0f;

  const int strow = tid >> 3;
  const int stcolb = (tid & 7) * 16;
  const int swzb = stcolb ^ ((strow & 7) << 4);
  const u16* ksrc = k + (long)b * SEQ * LDQ + h * 64 + (swzb >> 1);
  const u16* vsrc = vt + ((long)(h * 64 + strow)) * (NB * SEQ) + (long)b * SEQ + (swzb >> 1);
  const int sc16 = stcolb >> 1;

  auto STAGE = [&](int buf, int kt) {
    const u16* kr = ksrc + (long)(kt * 64 + strow) * LDQ;
    gl_lds16(kr, &Ks[buf][strow][sc16]);
    gl_lds16(kr + (long)32 * LDQ, &Ks[buf][strow + 32][sc16]);
    const u16* vr = vsrc + kt * 64;
    gl_lds16(vr, &Vs[buf][strow][sc16]);
    gl_lds16(vr + 32 * (NB * SEQ), &Vs[buf][strow + 32][sc16]);
  };

  const int rs = (lr & 7) << 3;
  const int c0 = (g * 8) ^ rs;
  const int c1 = (32 + g * 8) ^ rs;

  const u64* mrow = mbitsT + (qr0 + lr);

  u64 mb_cur = mrow[0];
  STAGE(0, 0);
  for (int kt = 0; kt < NT; kt++) {
    const int cur = kt & 1;
    wait_vmcnt<0>();                           // own stage(t)+mask(t) drained
    __builtin_amdgcn_sched_barrier(0);
    __builtin_amdgcn_s_barrier();              // all compute(t-1) done; tile t valid
    u64 mb_new = 0;
    if (kt + 1 < NT) {
      mb_new = mrow[(long)(kt + 1) * SEQ];
      STAGE(cur ^ 1, kt + 1);                  // flies across this compute phase
    }

    f32x4 sf[4];
    __builtin_amdgcn_s_setprio(1);
#pragma unroll
    for (int n = 0; n < 4; n++) {
      bf16x8 kb0 = *(const bf16x8*)&Ks[cur][n * 16 + lr][c0];
      bf16x8 kb1 = *(const bf16x8*)&Ks[cur][n * 16 + lr][c1];
      sf[n] = __builtin_amdgcn_mfma_f32_16x16x32_bf16(kb0, qf0, (f32x4)0.0f, 0, 0, 0);
      sf[n] = __builtin_amdgcn_mfma_f32_16x16x32_bf16(kb1, qf1, sf[n], 0, 0, 0);
    }
    __builtin_amdgcn_s_setprio(0);
    u64 tsh = mb_cur >> (4 * g);
    u32 mlo = (u32)tsh, mhi = (u32)(tsh >> 32);
#pragma unroll
    for (int n = 0; n < 4; n++) {
      u32 w = (n < 2) ? mlo : mhi;
#pragma unroll
      for (int r = 0; r < 4; r++) {
        u32 bit = 1u << (16 * (n & 1) + r);
        sf[n][r] = (w & bit) ? sf[n][r] : NEGB;
      }
    }
    // P = exp2(s) via raw v_exp_f32 (1 instr); pack pairs via v_perm
#pragma unroll
    for (int n = 0; n < 4; n++) {
      union { float f; u32 i; } p0, p1, p2, p3;
      p0.f = hw_exp2(sf[n][0]); p1.f = hw_exp2(sf[n][1]);
      p2.f = hw_exp2(sf[n][2]); p3.f = hw_exp2(sf[n][3]);
      u32 w0 = __builtin_amdgcn_perm(p1.i, p0.i, 0x07060302u);
      u32 w1 = __builtin_amdgcn_perm(p3.i, p2.i, 0x07060302u);
      *(u32x2*)&Ps32[wave][lr][8 * n + 2 * g] = (u32x2){w0, w1};
    }
    asm volatile("" ::: "memory");             // order Ps writes vs reads (same wave)
    bf16x8 pf0 = *(const bf16x8*)&Ps32[wave][lr][4 * g];
    bf16x8 pf1 = *(const bf16x8*)&Ps32[wave][lr][16 + 4 * g];
    __builtin_amdgcn_s_setprio(1);
    lsum = __builtin_amdgcn_mfma_f32_16x16x32_bf16(onesf, pf0, lsum, 0, 0, 0);
    lsum = __builtin_amdgcn_mfma_f32_16x16x32_bf16(onesf, pf1, lsum, 0, 0, 0);
#pragma unroll
    for (int db = 0; db < 4; db++) {
      bf16x8 v0 = *(const bf16x8*)&Vs[cur][db * 16 + lr][c0];
      bf16x8 v1 = *(const bf16x8*)&Vs[cur][db * 16 + lr][c1];
      oacc[db] = __builtin_amdgcn_mfma_f32_16x16x32_bf16(v0, pf0, oacc[db], 0, 0, 0);
      oacc[db] = __builtin_amdgcn_mfma_f32_16x16x32_bf16(v1, pf1, oacc[db], 0, 0, 0);
    }
    __builtin_amdgcn_s_setprio(0);
    mb_cur = mb_new;
  }
  float inv = 1.0f / lsum[0];
  long row = (long)b * SEQ + qr0 + lr;
#pragma unroll
  for (int db = 0; db < 4; db++) {
    u32 lo = ((u32)f2bf(oacc[db][1] * inv) << 16) | f2bf(oacc[db][0] * inv);
    u32 hi = ((u32)f2bf(oacc[db][3] * inv) << 16) | f2bf(oacc[db][2] * inv);
    *(u32x2*)(o_ + row * DM + h * 64 + db * 16 + g * 4) = (u32x2){lo, hi};
  }
}

extern "C" void kernel_launch(void* const* d_in, const int* in_sizes, int n_in,
                              void* d_out, int out_size, void* d_ws, size_t ws_size,
                              hipStream_t stream) {
  const float* x      = (const float*)d_in[0];
  const int*   mask   = (const int*)d_in[1];
  const float* wq     = (const float*)d_in[2];
  const float* bq     = (const float*)d_in[3];
  const float* wk     = (const float*)d_in[4];
  const float* bk     = (const float*)d_in[5];
  const float* wv     = (const float*)d_in[6];
  const float* bv     = (const float*)d_in[7];
  const float* wo     = (const float*)d_in[8];
  const float* bo     = (const float*)d_in[9];
  const float* w1     = (const float*)d_in[10];
  const float* b1     = (const float*)d_in[11];
  const float* w2     = (const float*)d_in[12];
  const float* b2     = (const float*)d_in[13];
  const float* alpha1 = (const float*)d_in[14];
  const float* beta1  = (const float*)d_in[15];
  const float* alpha2 = (const float*)d_in[16];
  const float* beta2  = (const float*)d_in[17];
  float* outf = (float*)d_out;

  // ---- workspace layout (~52.6 MiB) ----
  char* ws = (char*)d_ws;
  size_t off = 0;
  auto alloc = [&](size_t bytes) {
    void* p = ws + off;
    off += (bytes + 255) & ~(size_t)255;
    return p;
  };
  const size_t DD = (size_t)DM * DM * 2;
  const size_t DF = (size_t)DM * 3072 * 2;
  const size_t ROWS = (size_t)NB * SEQ;
  const size_t ACT = ROWS * DM * 2;

  u16* wqkvt = (u16*)alloc(3 * DD);
  u16* wot   = (u16*)alloc(DD);
  u16* w1t   = (u16*)alloc(DF);
  u16* w2t   = (u16*)alloc(DF);
  float* bqkv = (float*)alloc(3 * DM * 4);
  u64* mbitsT = (u64*)alloc((size_t)(SEQ / 64) * SEQ * 8);  // [32][2048] 512KB
  u16* h     = (u16*)alloc(ACT);
  u16* qkv   = (u16*)alloc(ROWS * 3 * DM * 2);
  u16* vtb   = (u16*)alloc(ACT);
  u16* ob    = (u16*)alloc(ACT);
  u16* fb = qkv;           // [4096][3072] bf16 over dead qkv|vtb
  u16* h2 = h;
  float* x1 = outf;        // d_out doubles as x1

  dim3 blk(256);
  prep_kernel<<<dim3(23305), blk, 0, stream>>>(wq, wk, wv, wo, w1, w2, bq, bk, bv,
                                               mask, wqkvt, wot, w1t, w2t, bqkv, mbitsT);

  ln_kernel<<<ROWS, blk, 0, stream>>>(x, alpha1, beta1, h);
  // fused QKV; V-tiles (n0 >= 1536) written transposed straight into vtb
  gemm_bt_kernel<128><<<dim3(576), blk, 0, stream>>>(
      h, wqkvt, bqkv, nullptr, qkv, nullptr, vtb, 2 * DM, 4096, 3 * DM, 768, 768, 0, 18, 0);
  attn_kernel<<<dim3(32 * NH * NB), blk, 0, stream>>>(qkv, vtb, mbitsT, ob);
  gemm_bt_kernel<64><<<dim3(384), blk, 0, stream>>>(
      ob, wot, bo, x, nullptr, x1, nullptr, 0, 4096, 768, 768, 768, 0, 12, 0);
  ln_kernel<<<ROWS, blk, 0, stream>>>(x1, alpha2, beta2, h2);
  gemm_bt_kernel<128><<<dim3(768), blk, 0, stream>>>(
      h2, w1t, b1, nullptr, fb, nullptr, nullptr, 0, 4096, 3072, 768, 768, 1, 24, 0);
  // FFN2 split-K x2: out(x1, fp32) += chunk partials via atomicAdd
  gemm_bt_kernel<64><<<dim3(768), blk, 0, stream>>>(
      fb, w2t, b2, nullptr, nullptr, outf, nullptr, 0, 4096, 768, 1536, 3072, 0, 12, 384);
}

// Round 20
// 201.255 us; speedup vs baseline: 1.3008x; 1.0138x over previous
//
#include <hip/hip_runtime.h>

typedef unsigned short u16;
typedef unsigned int u32;
typedef unsigned long long u64;
typedef __attribute__((ext_vector_type(8))) short bf16x8;
typedef __attribute__((ext_vector_type(4))) float f32x4;
typedef __attribute__((ext_vector_type(2))) unsigned int u32x2;

#define SEQ 2048
#define DM  768
#define NH  12
#define NB  2
#define LDQ (3 * DM)                    // 2304, row stride of fused qkv buffer

#define SCALE_Q 0.180336879f            // 0.125 * log2(e): folded into wq/bq
#define NEGB   -1.44269504e9f           // -1e9 * log2(e): mask value in exp2 domain

__device__ __forceinline__ float bf2f(u16 u) {
  union { u32 i; float f; } v; v.i = ((u32)u) << 16; return v.f;
}
__device__ __forceinline__ u16 f2bf(float f) {  // RNE (kernel outputs)
  union { float f; u32 i; } v; v.f = f;
  u32 r = v.i + 0x7FFFu + ((v.i >> 16) & 1u);
  return (u16)(r >> 16);
}
// raw HW exp2: 1 trans-pipe instr. Underflows big negatives (NEGB) to 0.
__device__ __forceinline__ float hw_exp2(float x) {
  float r;
  asm("v_exp_f32 %0, %1" : "=v"(r) : "v"(x));
  return r;
}
__device__ __forceinline__ void gl_lds16(const u16* g, u16* l) {
  __builtin_amdgcn_global_load_lds(
      (const __attribute__((address_space(1))) unsigned int*)g,
      (__attribute__((address_space(3))) unsigned int*)l, 16, 0, 0);
}
template<int N> __device__ __forceinline__ void wait_vmcnt() {
  if constexpr (N == 0) asm volatile("s_waitcnt vmcnt(0)" ::: "memory");
  else if constexpr (N == 3) asm volatile("s_waitcnt vmcnt(3)" ::: "memory");
  else if constexpr (N == 4) asm volatile("s_waitcnt vmcnt(4)" ::: "memory");
  else if constexpr (N == 5) asm volatile("s_waitcnt vmcnt(5)" ::: "memory");
}

// ------- merged prep: 6 weight transposes + bias concat + mask ballots --
__global__ __launch_bounds__(256) void prep_kernel(
    const float* __restrict__ wq, const float* __restrict__ wk,
    const float* __restrict__ wv, const float* __restrict__ wo,
    const float* __restrict__ w1, const float* __restrict__ w2,
    const float* __restrict__ bq, const float* __restrict__ bk,
    const float* __restrict__ bv, const int* __restrict__ mask,
    u16* __restrict__ wqkvt, u16* __restrict__ wot,
    u16* __restrict__ w1t, u16* __restrict__ w2t,
    float* __restrict__ bqkv, u64* __restrict__ mbitsT) {
  __shared__ float t[32][33];
  const int j = blockIdx.x, tid = threadIdx.x;
  const float* in = nullptr; u16* out = nullptr;
  int R = 0, C = 0, bx = 0, by = 0; float sc = 1.0f;
  if (j < 2304) {
    int which = j / 576, local = j % 576;
    in = which == 0 ? wq : which == 1 ? wk : which == 2 ? wv : wo;
    out = which == 3 ? wot : wqkvt + (size_t)which * DM * DM;
    sc = (which == 0) ? SCALE_Q : 1.0f;
    R = DM; C = DM; bx = local % 24; by = local / 24;
  } else if (j < 4608) {
    int local = j - 2304;
    in = w1; out = w1t; R = DM; C = 3072; bx = local % 96; by = local / 96;
  } else if (j < 6912) {
    int local = j - 4608;
    in = w2; out = w2t; R = 3072; C = DM; bx = local % 24; by = local / 24;
  } else if (j < 6921) {
    int i = (j - 6912) * 256 + tid;
    float v = (i < DM) ? bq[i] * SCALE_Q : (i < 2 * DM ? bk[i - DM] : bv[i - 2 * DM]);
    bqkv[i] = v;
    return;
  } else {
    int wid = (j - 6921) * 4 + (tid >> 6);      // (row, word)
    int lane = tid & 63;
    int row = wid >> 5, word = wid & 31;
    int m = mask[(long)row * SEQ + word * 64 + lane];
    u64 bb = __ballot(m != 0);
    if (lane == 0) mbitsT[(long)word * SEQ + row] = bb;  // transposed [32][2048]
    return;
  }
  long r0 = (long)by * 32, c0 = (long)bx * 32;
  int lc = tid & 31, wr = tid >> 5;
#pragma unroll
  for (int i = 0; i < 4; i++) {
    int row = wr + i * 8;
    t[row][lc] = in[(r0 + row) * C + c0 + lc];
  }
  __syncthreads();
#pragma unroll
  for (int i = 0; i < 4; i++) {
    int row = wr + i * 8;
    out[(c0 + row) * R + r0 + lc] = f2bf(t[lc][row] * sc);
  }
}

// ------- LayerNorm: fp32 in -> bf16 out (unbiased var, eps on std) -----
__global__ __launch_bounds__(256) void ln_kernel(
    const float* __restrict__ x, const float* __restrict__ alpha,
    const float* __restrict__ beta, u16* __restrict__ out) {
  long row = blockIdx.x;
  const float* xr = x + row * DM;
  int tid = threadIdx.x;
  float v[3];
  float s = 0.f, sq = 0.f;
#pragma unroll
  for (int i = 0; i < 3; i++) {
    v[i] = xr[tid + i * 256];
    s += v[i]; sq += v[i] * v[i];
  }
#pragma unroll
  for (int off = 32; off >= 1; off >>= 1) {
    s += __shfl_down(s, off, 64);
    sq += __shfl_down(sq, off, 64);
  }
  __shared__ float ss[4], ssq[4];
  int wave = tid >> 6;
  if ((tid & 63) == 0) { ss[wave] = s; ssq[wave] = sq; }
  __syncthreads();
  float ts = ss[0] + ss[1] + ss[2] + ss[3];
  float tsq = ssq[0] + ssq[1] + ssq[2] + ssq[3];
  float mean = ts * (1.0f / (float)DM);
  float var = fmaxf((tsq - ts * mean) * (1.0f / (float)(DM - 1)), 0.0f);
  float inv = 1.0f / (sqrtf(var) + 1e-6f);
#pragma unroll
  for (int i = 0; i < 3; i++) {
    int c = tid + i * 256;
    out[row * DM + c] = f2bf(alpha[c] * (v[i] - mean) * inv + beta[c]);
  }
}

// - GEMM: C[M,N] = A[M,Kld] @ Bt[N,Kld]^T + bias (+res) (+relu) ---------
// S=3 counted-vmcnt pipeline (T4), 1D grid + XCD swizzle (T1).
// Split-K (wgPerChunk>0): 2 chunks, fp32 atomicAdd into Cf (chunk0 adds bias).
// Vt != nullptr: n-tiles with n0 >= vcol0 write TRANSPOSED to Vt[col-vcol0][row]
// (4 consecutive rows packed per 8B store) instead of Cb -- fuses V transpose.
template<int BN>
__global__ __launch_bounds__(256, 2) void gemm_bt_kernel(
    const u16* __restrict__ A, const u16* __restrict__ Bt,
    const float* __restrict__ bias, const float* res,
    u16* Cb, float* Cf, u16* Vt, int vcol0, int M, int N, int K, int Kld,
    int relu, int nx, int wgPerChunk) {
  constexpr int NJ = BN / 32;
  constexpr int L = (BN == 128) ? 4 : 3;      // gl_lds ops per STAGE
  __shared__ __align__(16) u16 As[3][128][32];
  __shared__ __align__(16) u16 Bs[3][BN][32];
  const int tid = threadIdx.x;
  const int lane = tid & 63, wave = tid >> 6;
  const int g = lane >> 4, lr = lane & 15;
  const int wm = (wave >> 1) * 64, wn = (wave & 1) * (BN / 2);
  const int o = blockIdx.x;
  int wg = (o & 7) * ((int)gridDim.x >> 3) + (o >> 3);
  int chunk = 0;
  if (wgPerChunk) { chunk = wg / wgPerChunk; wg -= chunk * wgPerChunk; }
  const int bx = wg % nx, by = wg / nx;
  const long m0 = (long)by * 128;
  const long n0 = (long)bx * BN;
  const int srow = tid >> 2;
  const int scol = (tid & 3) * 8;
  const long koff = (long)chunk * K;

  const u16* aSrc = A + (m0 + srow) * Kld + koff + scol;
  const u16* bSrc = Bt + (n0 + srow) * Kld + koff + scol;

  auto STAGE = [&](int buf, int t) {
    const int k0 = t * 32;
    gl_lds16(aSrc + k0, &As[buf][srow][scol]);
    gl_lds16(aSrc + (long)64 * Kld + k0, &As[buf][srow + 64][scol]);
    gl_lds16(bSrc + k0, &Bs[buf][srow][scol]);
    if (BN == 128) gl_lds16(bSrc + (long)64 * Kld + k0, &Bs[buf][srow + 64][scol]);
  };

  f32x4 acc[4][NJ];
#pragma unroll
  for (int i = 0; i < 4; i++)
#pragma unroll
    for (int j = 0; j < NJ; j++) acc[i][j] = (f32x4)0.0f;

  const int nk = K / 32;
  STAGE(0, 0);
  STAGE(1, 1);
  for (int t = 0; t < nk; t++) {
    const int cur = t % 3;
    if (t + 1 < nk) wait_vmcnt<L>(); else wait_vmcnt<0>();
    __builtin_amdgcn_sched_barrier(0);
    __builtin_amdgcn_s_barrier();
    bf16x8 af[4], bfr[NJ];
#pragma unroll
    for (int i = 0; i < 4; i++) af[i] = *(const bf16x8*)&As[cur][wm + i * 16 + lr][g * 8];
#pragma unroll
    for (int j = 0; j < NJ; j++) bfr[j] = *(const bf16x8*)&Bs[cur][wn + j * 16 + lr][g * 8];
#pragma unroll
    for (int i = 0; i < 4; i++)
#pragma unroll
      for (int j = 0; j < NJ; j++)
        acc[i][j] = __builtin_amdgcn_mfma_f32_16x16x32_bf16(af[i], bfr[j], acc[i][j], 0, 0, 0);
    if (t + 2 < nk) STAGE((t + 2) % 3, t + 2);
  }
  const bool isV = (Vt != nullptr) && (n0 >= vcol0);   // block-uniform
#pragma unroll
  for (int j = 0; j < NJ; j++) {
    long col = n0 + wn + j * 16 + lr;
    float bv = (bias && chunk == 0) ? bias[col] : 0.0f;
#pragma unroll
    for (int i = 0; i < 4; i++) {
      float vals[4];
#pragma unroll
      for (int r = 0; r < 4; r++) {
        long row = m0 + wm + i * 16 + g * 4 + r;
        float v = acc[i][j][r] + bv;
        if (res) v += res[row * N + col];
        if (relu) v = fmaxf(v, 0.0f);
        vals[r] = v;
        if (!isV) {
          if (wgPerChunk)  atomicAdd(&Cf[row * N + col], v);
          else if (Cb)     Cb[row * N + col] = f2bf(v);
          else             Cf[row * N + col] = v;
        }
      }
      if (isV) {
        // transposed V store: Vt[col - vcol0][row0..row0+3] as one 8B write
        long row0 = m0 + wm + i * 16 + g * 4;
        u32 lo = ((u32)f2bf(vals[1]) << 16) | f2bf(vals[0]);
        u32 hi = ((u32)f2bf(vals[3]) << 16) | f2bf(vals[2]);
        *(u32x2*)(Vt + (col - vcol0) * (long)(NB * SEQ) + row0) = (u32x2){lo, hi};
      }
    }
  }
}

// ------- flash attention: swapped QK^T, ONE barrier per KV tile --------
__global__ __launch_bounds__(256, 3) void attn_kernel(
    const u16* __restrict__ qkv, const u16* __restrict__ vt,
    const u64* __restrict__ mbitsT, u16* __restrict__ o_) {
  __shared__ __align__(16) u16 Ks[2][64][64];
  __shared__ __align__(16) u16 Vs[2][64][64];
  __shared__ __align__(16) u32 Ps32[4][16][36];
  const int o = blockIdx.x;
  const int wg = (o & 7) * 96 + (o >> 3);
  const int qt = wg & 31, h = (wg >> 5) % NH, b = wg / (32 * NH);
  const int tid = threadIdx.x;
  const int lane = tid & 63, wave = tid >> 6;
  const int g = lane >> 4, lr = lane & 15;
  const int qr0 = qt * 64 + wave * 16;
  const int NT = SEQ / 64;

  const u16* q = qkv;
  const u16* k = qkv + DM;

  const long qbase = ((long)(b * SEQ + qr0 + lr)) * LDQ + h * 64;
  bf16x8 qf0 = *(const bf16x8*)(q + qbase + g * 8);
  bf16x8 qf1 = *(const bf16x8*)(q + qbase + 32 + g * 8);

  bf16x8 onesf;
#pragma unroll
  for (int j = 0; j < 8; j++) onesf[j] = (short)0x3F80;

  f32x4 lsum = (f32x4)0.0f;
  f32x4 oacc[4];                               // O^T: row d=db*16+g*4+r, col q=lr
#pragma unroll
  for (int d = 0; d < 4; d++) oacc[d] = (f32x4)0.0f;

  const int strow = tid >> 3;
  const int stcolb = (tid & 7) * 16;
  const int swzb = stcolb ^ ((strow & 7) << 4);
  const u16* ksrc = k + (long)b * SEQ * LDQ + h * 64 + (swzb >> 1);
  const u16* vsrc = vt + ((long)(h * 64 + strow)) * (NB * SEQ) + (long)b * SEQ + (swzb >> 1);
  const int sc16 = stcolb >> 1;

  auto STAGE = [&](int buf, int kt) {
    const u16* kr = ksrc + (long)(kt * 64 + strow) * LDQ;
    gl_lds16(kr, &Ks[buf][strow][sc16]);
    gl_lds16(kr + (long)32 * LDQ, &Ks[buf][strow + 32][sc16]);
    const u16* vr = vsrc + kt * 64;
    gl_lds16(vr, &Vs[buf][strow][sc16]);
    gl_lds16(vr + 32 * (NB * SEQ), &Vs[buf][strow + 32][sc16]);
  };

  const int rs = (lr & 7) << 3;
  const int c0 = (g * 8) ^ rs;
  const int c1 = (32 + g * 8) ^ rs;

  const u64* mrow = mbitsT + (qr0 + lr);

  u64 mb_cur = mrow[0];
  STAGE(0, 0);
  for (int kt = 0; kt < NT; kt++) {
    const int cur = kt & 1;
    wait_vmcnt<0>();                           // own stage(t)+mask(t) drained
    __builtin_amdgcn_sched_barrier(0);
    __builtin_amdgcn_s_barrier();              // all compute(t-1) done; tile t valid
    u64 mb_new = 0;
    if (kt + 1 < NT) {
      mb_new = mrow[(long)(kt + 1) * SEQ];
      STAGE(cur ^ 1, kt + 1);                  // flies across this compute phase
    }

    f32x4 sf[4];
    __builtin_amdgcn_s_setprio(1);
#pragma unroll
    for (int n = 0; n < 4; n++) {
      bf16x8 kb0 = *(const bf16x8*)&Ks[cur][n * 16 + lr][c0];
      bf16x8 kb1 = *(const bf16x8*)&Ks[cur][n * 16 + lr][c1];
      sf[n] = __builtin_amdgcn_mfma_f32_16x16x32_bf16(kb0, qf0, (f32x4)0.0f, 0, 0, 0);
      sf[n] = __builtin_amdgcn_mfma_f32_16x16x32_bf16(kb1, qf1, sf[n], 0, 0, 0);
    }
    __builtin_amdgcn_s_setprio(0);
    u64 tsh = mb_cur >> (4 * g);
    u32 mlo = (u32)tsh, mhi = (u32)(tsh >> 32);
#pragma unroll
    for (int n = 0; n < 4; n++) {
      u32 w = (n < 2) ? mlo : mhi;
#pragma unroll
      for (int r = 0; r < 4; r++) {
        u32 bit = 1u << (16 * (n & 1) + r);
        sf[n][r] = (w & bit) ? sf[n][r] : NEGB;
      }
    }
    // P = exp2(s) via raw v_exp_f32 (1 instr); pack pairs via v_perm
#pragma unroll
    for (int n = 0; n < 4; n++) {
      union { float f; u32 i; } p0, p1, p2, p3;
      p0.f = hw_exp2(sf[n][0]); p1.f = hw_exp2(sf[n][1]);
      p2.f = hw_exp2(sf[n][2]); p3.f = hw_exp2(sf[n][3]);
      u32 w0 = __builtin_amdgcn_perm(p1.i, p0.i, 0x07060302u);
      u32 w1 = __builtin_amdgcn_perm(p3.i, p2.i, 0x07060302u);
      *(u32x2*)&Ps32[wave][lr][8 * n + 2 * g] = (u32x2){w0, w1};
    }
    asm volatile("" ::: "memory");             // order Ps writes vs reads (same wave)
    bf16x8 pf0 = *(const bf16x8*)&Ps32[wave][lr][4 * g];
    bf16x8 pf1 = *(const bf16x8*)&Ps32[wave][lr][16 + 4 * g];
    __builtin_amdgcn_s_setprio(1);
    lsum = __builtin_amdgcn_mfma_f32_16x16x32_bf16(onesf, pf0, lsum, 0, 0, 0);
    lsum = __builtin_amdgcn_mfma_f32_16x16x32_bf16(onesf, pf1, lsum, 0, 0, 0);
#pragma unroll
    for (int db = 0; db < 4; db++) {
      bf16x8 v0 = *(const bf16x8*)&Vs[cur][db * 16 + lr][c0];
      bf16x8 v1 = *(const bf16x8*)&Vs[cur][db * 16 + lr][c1];
      oacc[db] = __builtin_amdgcn_mfma_f32_16x16x32_bf16(v0, pf0, oacc[db], 0, 0, 0);
      oacc[db] = __builtin_amdgcn_mfma_f32_16x16x32_bf16(v1, pf1, oacc[db], 0, 0, 0);
    }
    __builtin_amdgcn_s_setprio(0);
    mb_cur = mb_new;
  }
  float inv = 1.0f / lsum[0];
  long row = (long)b * SEQ + qr0 + lr;
#pragma unroll
  for (int db = 0; db < 4; db++) {
    u32 lo = ((u32)f2bf(oacc[db][1] * inv) << 16) | f2bf(oacc[db][0] * inv);
    u32 hi = ((u32)f2bf(oacc[db][3] * inv) << 16) | f2bf(oacc[db][2] * inv);
    *(u32x2*)(o_ + row * DM + h * 64 + db * 16 + g * 4) = (u32x2){lo, hi};
  }
}

extern "C" void kernel_launch(void* const* d_in, const int* in_sizes, int n_in,
                              void* d_out, int out_size, void* d_ws, size_t ws_size,
                              hipStream_t stream) {
  const float* x      = (const float*)d_in[0];
  const int*   mask   = (const int*)d_in[1];
  const float* wq     = (const float*)d_in[2];
  const float* bq     = (const float*)d_in[3];
  const float* wk     = (const float*)d_in[4];
  const float* bk     = (const float*)d_in[5];
  const float* wv     = (const float*)d_in[6];
  const float* bv     = (const float*)d_in[7];
  const float* wo     = (const float*)d_in[8];
  const float* bo     = (const float*)d_in[9];
  const float* w1     = (const float*)d_in[10];
  const float* b1     = (const float*)d_in[11];
  const float* w2     = (const float*)d_in[12];
  const float* b2     = (const float*)d_in[13];
  const float* alpha1 = (const float*)d_in[14];
  const float* beta1  = (const float*)d_in[15];
  const float* alpha2 = (const float*)d_in[16];
  const float* beta2  = (const float*)d_in[17];
  float* outf = (float*)d_out;

  // ---- workspace layout (~52.6 MiB) ----
  char* ws = (char*)d_ws;
  size_t off = 0;
  auto alloc = [&](size_t bytes) {
    void* p = ws + off;
    off += (bytes + 255) & ~(size_t)255;
    return p;
  };
  const size_t DD = (size_t)DM * DM * 2;
  const size_t DF = (size_t)DM * 3072 * 2;
  const size_t ROWS = (size_t)NB * SEQ;
  const size_t ACT = ROWS * DM * 2;

  u16* wqkvt = (u16*)alloc(3 * DD);
  u16* wot   = (u16*)alloc(DD);
  u16* w1t   = (u16*)alloc(DF);
  u16* w2t   = (u16*)alloc(DF);
  float* bqkv = (float*)alloc(3 * DM * 4);
  u64* mbitsT = (u64*)alloc((size_t)(SEQ / 64) * SEQ * 8);  // [32][2048] 512KB
  u16* h     = (u16*)alloc(ACT);
  u16* qkv   = (u16*)alloc(ROWS * 3 * DM * 2);
  u16* vtb   = (u16*)alloc(ACT);
  u16* ob    = (u16*)alloc(ACT);
  u16* fb = qkv;           // [4096][3072] bf16 over dead qkv|vtb
  u16* h2 = h;
  float* x1 = outf;        // d_out doubles as x1

  dim3 blk(256);
  prep_kernel<<<dim3(23305), blk, 0, stream>>>(wq, wk, wv, wo, w1, w2, bq, bk, bv,
                                               mask, wqkvt, wot, w1t, w2t, bqkv, mbitsT);

  ln_kernel<<<ROWS, blk, 0, stream>>>(x, alpha1, beta1, h);
  // fused QKV; V-tiles (n0 >= 1536) written transposed straight into vtb
  gemm_bt_kernel<128><<<dim3(576), blk, 0, stream>>>(
      h, wqkvt, bqkv, nullptr, qkv, nullptr, vtb, 2 * DM, 4096, 3 * DM, 768, 768, 0, 18, 0);
  attn_kernel<<<dim3(32 * NH * NB), blk, 0, stream>>>(qkv, vtb, mbitsT, ob);
  gemm_bt_kernel<64><<<dim3(384), blk, 0, stream>>>(
      ob, wot, bo, x, nullptr, x1, nullptr, 0, 4096, 768, 768, 768, 0, 12, 0);
  ln_kernel<<<ROWS, blk, 0, stream>>>(x1, alpha2, beta2, h2);
  gemm_bt_kernel<128><<<dim3(768), blk, 0, stream>>>(
      h2, w1t, b1, nullptr, fb, nullptr, nullptr, 0, 4096, 3072, 768, 768, 1, 24, 0);
  // FFN2 split-K x2, BN=128 (nx=6): 384 blocks, 48 iters of 16 MFMA;
  // total ds_read x0.67, barriers x0.5 vs BN=64 variant; same 25 MB atomics.
  gemm_bt_kernel<128><<<dim3(384), blk, 0, stream>>>(
      fb, w2t, b2, nullptr, nullptr, outf, nullptr, 0, 4096, 768, 1536, 3072, 0, 6, 192);
}

// Round 21
// 200.086 us; speedup vs baseline: 1.3084x; 1.0058x over previous
//
#include <hip/hip_runtime.h>

typedef unsigned short u16;
typedef unsigned int u32;
typedef unsigned long long u64;
typedef __attribute__((ext_vector_type(8))) short bf16x8;
typedef __attribute__((ext_vector_type(4))) float f32x4;
typedef __attribute__((ext_vector_type(2))) unsigned int u32x2;

#define SEQ 2048
#define DM  768
#define NH  12
#define NB  2
#define LDQ (3 * DM)                    // 2304, row stride of fused qkv buffer

#define SCALE_Q 0.180336879f            // 0.125 * log2(e): folded into wq/bq
#define NEGB   -1.44269504e9f           // -1e9 * log2(e): mask value in exp2 domain

__device__ __forceinline__ float bf2f(u16 u) {
  union { u32 i; float f; } v; v.i = ((u32)u) << 16; return v.f;
}
__device__ __forceinline__ u16 f2bf(float f) {  // RNE (kernel outputs)
  union { float f; u32 i; } v; v.f = f;
  u32 r = v.i + 0x7FFFu + ((v.i >> 16) & 1u);
  return (u16)(r >> 16);
}
// raw HW exp2: 1 trans-pipe instr. Underflows big negatives (NEGB) to 0.
__device__ __forceinline__ float hw_exp2(float x) {
  float r;
  asm("v_exp_f32 %0, %1" : "=v"(r) : "v"(x));
  return r;
}
__device__ __forceinline__ void gl_lds16(const u16* g, u16* l) {
  __builtin_amdgcn_global_load_lds(
      (const __attribute__((address_space(1))) unsigned int*)g,
      (__attribute__((address_space(3))) unsigned int*)l, 16, 0, 0);
}
template<int N> __device__ __forceinline__ void wait_vmcnt() {
  if constexpr (N == 0) asm volatile("s_waitcnt vmcnt(0)" ::: "memory");
  else if constexpr (N == 3) asm volatile("s_waitcnt vmcnt(3)" ::: "memory");
  else if constexpr (N == 4) asm volatile("s_waitcnt vmcnt(4)" ::: "memory");
  else if constexpr (N == 5) asm volatile("s_waitcnt vmcnt(5)" ::: "memory");
}

// ------- merged prep: 6 weight transposes + bias concat + mask ballots --
__global__ __launch_bounds__(256) void prep_kernel(
    const float* __restrict__ wq, const float* __restrict__ wk,
    const float* __restrict__ wv, const float* __restrict__ wo,
    const float* __restrict__ w1, const float* __restrict__ w2,
    const float* __restrict__ bq, const float* __restrict__ bk,
    const float* __restrict__ bv, const int* __restrict__ mask,
    u16* __restrict__ wqkvt, u16* __restrict__ wot,
    u16* __restrict__ w1t, u16* __restrict__ w2t,
    float* __restrict__ bqkv, u64* __restrict__ mbitsT) {
  __shared__ float t[32][33];
  const int j = blockIdx.x, tid = threadIdx.x;
  const float* in = nullptr; u16* out = nullptr;
  int R = 0, C = 0, bx = 0, by = 0; float sc = 1.0f;
  if (j < 2304) {
    int which = j / 576, local = j % 576;
    in = which == 0 ? wq : which == 1 ? wk : which == 2 ? wv : wo;
    out = which == 3 ? wot : wqkvt + (size_t)which * DM * DM;
    sc = (which == 0) ? SCALE_Q : 1.0f;
    R = DM; C = DM; bx = local % 24; by = local / 24;
  } else if (j < 4608) {
    int local = j - 2304;
    in = w1; out = w1t; R = DM; C = 3072; bx = local % 96; by = local / 96;
  } else if (j < 6912) {
    int local = j - 4608;
    in = w2; out = w2t; R = 3072; C = DM; bx = local % 24; by = local / 24;
  } else if (j < 6921) {
    int i = (j - 6912) * 256 + tid;
    float v = (i < DM) ? bq[i] * SCALE_Q : (i < 2 * DM ? bk[i - DM] : bv[i - 2 * DM]);
    bqkv[i] = v;
    return;
  } else {
    int wid = (j - 6921) * 4 + (tid >> 6);      // (row, word)
    int lane = tid & 63;
    int row = wid >> 5, word = wid & 31;
    int m = mask[(long)row * SEQ + word * 64 + lane];
    u64 bb = __ballot(m != 0);
    if (lane == 0) mbitsT[(long)word * SEQ + row] = bb;  // transposed [32][2048]
    return;
  }
  long r0 = (long)by * 32, c0 = (long)bx * 32;
  int lc = tid & 31, wr = tid >> 5;
#pragma unroll
  for (int i = 0; i < 4; i++) {
    int row = wr + i * 8;
    t[row][lc] = in[(r0 + row) * C + c0 + lc];
  }
  __syncthreads();
#pragma unroll
  for (int i = 0; i < 4; i++) {
    int row = wr + i * 8;
    out[(c0 + row) * R + r0 + lc] = f2bf(t[lc][row] * sc);
  }
}

// ------- LayerNorm: fp32 in -> bf16 out (unbiased var, eps on std) -----
__global__ __launch_bounds__(256) void ln_kernel(
    const float* __restrict__ x, const float* __restrict__ alpha,
    const float* __restrict__ beta, u16* __restrict__ out) {
  long row = blockIdx.x;
  const float* xr = x + row * DM;
  int tid = threadIdx.x;
  float v[3];
  float s = 0.f, sq = 0.f;
#pragma unroll
  for (int i = 0; i < 3; i++) {
    v[i] = xr[tid + i * 256];
    s += v[i]; sq += v[i] * v[i];
  }
#pragma unroll
  for (int off = 32; off >= 1; off >>= 1) {
    s += __shfl_down(s, off, 64);
    sq += __shfl_down(sq, off, 64);
  }
  __shared__ float ss[4], ssq[4];
  int wave = tid >> 6;
  if ((tid & 63) == 0) { ss[wave] = s; ssq[wave] = sq; }
  __syncthreads();
  float ts = ss[0] + ss[1] + ss[2] + ss[3];
  float tsq = ssq[0] + ssq[1] + ssq[2] + ssq[3];
  float mean = ts * (1.0f / (float)DM);
  float var = fmaxf((tsq - ts * mean) * (1.0f / (float)(DM - 1)), 0.0f);
  float inv = 1.0f / (sqrtf(var) + 1e-6f);
#pragma unroll
  for (int i = 0; i < 3; i++) {
    int c = tid + i * 256;
    out[row * DM + c] = f2bf(alpha[c] * (v[i] - mean) * inv + beta[c]);
  }
}

// - GEMM: C[M,N] = A[M,Kld] @ Bt[N,Kld]^T + bias (+res) (+relu) ---------
// S=3 counted-vmcnt pipeline (T4), 1D grid + XCD swizzle (T1).
// Split-K (wgPerChunk>0): 2 chunks, fp32 atomicAdd into Cf (chunk0 adds bias).
// Vt != nullptr: n-tiles with n0 >= vcol0 write TRANSPOSED to Vt[col-vcol0][row]
// (4 consecutive rows packed per 8B store) instead of Cb -- fuses V transpose.
template<int BN>
__global__ __launch_bounds__(256, 2) void gemm_bt_kernel(
    const u16* __restrict__ A, const u16* __restrict__ Bt,
    const float* __restrict__ bias, const float* res,
    u16* Cb, float* Cf, u16* Vt, int vcol0, int M, int N, int K, int Kld,
    int relu, int nx, int wgPerChunk) {
  constexpr int NJ = BN / 32;
  constexpr int L = (BN == 128) ? 4 : 3;      // gl_lds ops per STAGE
  __shared__ __align__(16) u16 As[3][128][32];
  __shared__ __align__(16) u16 Bs[3][BN][32];
  const int tid = threadIdx.x;
  const int lane = tid & 63, wave = tid >> 6;
  const int g = lane >> 4, lr = lane & 15;
  const int wm = (wave >> 1) * 64, wn = (wave & 1) * (BN / 2);
  const int o = blockIdx.x;
  int wg = (o & 7) * ((int)gridDim.x >> 3) + (o >> 3);
  int chunk = 0;
  if (wgPerChunk) { chunk = wg / wgPerChunk; wg -= chunk * wgPerChunk; }
  const int bx = wg % nx, by = wg / nx;
  const long m0 = (long)by * 128;
  const long n0 = (long)bx * BN;
  const int srow = tid >> 2;
  const int scol = (tid & 3) * 8;
  const long koff = (long)chunk * K;

  const u16* aSrc = A + (m0 + srow) * Kld + koff + scol;
  const u16* bSrc = Bt + (n0 + srow) * Kld + koff + scol;

  auto STAGE = [&](int buf, int t) {
    const int k0 = t * 32;
    gl_lds16(aSrc + k0, &As[buf][srow][scol]);
    gl_lds16(aSrc + (long)64 * Kld + k0, &As[buf][srow + 64][scol]);
    gl_lds16(bSrc + k0, &Bs[buf][srow][scol]);
    if (BN == 128) gl_lds16(bSrc + (long)64 * Kld + k0, &Bs[buf][srow + 64][scol]);
  };

  f32x4 acc[4][NJ];
#pragma unroll
  for (int i = 0; i < 4; i++)
#pragma unroll
    for (int j = 0; j < NJ; j++) acc[i][j] = (f32x4)0.0f;

  const int nk = K / 32;
  STAGE(0, 0);
  STAGE(1, 1);
  for (int t = 0; t < nk; t++) {
    const int cur = t % 3;
    if (t + 1 < nk) wait_vmcnt<L>(); else wait_vmcnt<0>();
    __builtin_amdgcn_sched_barrier(0);
    __builtin_amdgcn_s_barrier();
    bf16x8 af[4], bfr[NJ];
#pragma unroll
    for (int i = 0; i < 4; i++) af[i] = *(const bf16x8*)&As[cur][wm + i * 16 + lr][g * 8];
#pragma unroll
    for (int j = 0; j < NJ; j++) bfr[j] = *(const bf16x8*)&Bs[cur][wn + j * 16 + lr][g * 8];
#pragma unroll
    for (int i = 0; i < 4; i++)
#pragma unroll
      for (int j = 0; j < NJ; j++)
        acc[i][j] = __builtin_amdgcn_mfma_f32_16x16x32_bf16(af[i], bfr[j], acc[i][j], 0, 0, 0);
    if (t + 2 < nk) STAGE((t + 2) % 3, t + 2);
  }
  const bool isV = (Vt != nullptr) && (n0 >= vcol0);   // block-uniform
#pragma unroll
  for (int j = 0; j < NJ; j++) {
    long col = n0 + wn + j * 16 + lr;
    float bv = (bias && chunk == 0) ? bias[col] : 0.0f;
#pragma unroll
    for (int i = 0; i < 4; i++) {
      float vals[4];
#pragma unroll
      for (int r = 0; r < 4; r++) {
        long row = m0 + wm + i * 16 + g * 4 + r;
        float v = acc[i][j][r] + bv;
        if (res) v += res[row * N + col];
        if (relu) v = fmaxf(v, 0.0f);
        vals[r] = v;
        if (!isV) {
          if (wgPerChunk)  atomicAdd(&Cf[row * N + col], v);
          else if (Cb)     Cb[row * N + col] = f2bf(v);
          else             Cf[row * N + col] = v;
        }
      }
      if (isV) {
        // transposed V store: Vt[col - vcol0][row0..row0+3] as one 8B write
        long row0 = m0 + wm + i * 16 + g * 4;
        u32 lo = ((u32)f2bf(vals[1]) << 16) | f2bf(vals[0]);
        u32 hi = ((u32)f2bf(vals[3]) << 16) | f2bf(vals[2]);
        *(u32x2*)(Vt + (col - vcol0) * (long)(NB * SEQ) + row0) = (u32x2){lo, hi};
      }
    }
  }
}

// ------- flash attention: swapped QK^T, ONE barrier per KV tile --------
// LDS = 40960 B exactly -> 4 blocks/CU (16 waves). Ps uses r7's XOR-swizzled
// stride-32 layout (786K conflicts measured, vs 2.36M for the pad-36 layout).
__global__ __launch_bounds__(256, 4) void attn_kernel(
    const u16* __restrict__ qkv, const u16* __restrict__ vt,
    const u64* __restrict__ mbitsT, u16* __restrict__ o_) {
  __shared__ __align__(16) u16 Ks[2][64][64];
  __shared__ __align__(16) u16 Vs[2][64][64];
  __shared__ __align__(16) u32 Ps32[4][16][32];   // stride 32, XOR-swizzled
  const int o = blockIdx.x;
  const int wg = (o & 7) * 96 + (o >> 3);
  const int qt = wg & 31, h = (wg >> 5) % NH, b = wg / (32 * NH);
  const int tid = threadIdx.x;
  const int lane = tid & 63, wave = tid >> 6;
  const int g = lane >> 4, lr = lane & 15;
  const int qr0 = qt * 64 + wave * 16;
  const int NT = SEQ / 64;

  const u16* q = qkv;
  const u16* k = qkv + DM;

  const long qbase = ((long)(b * SEQ + qr0 + lr)) * LDQ + h * 64;
  bf16x8 qf0 = *(const bf16x8*)(q + qbase + g * 8);
  bf16x8 qf1 = *(const bf16x8*)(q + qbase + 32 + g * 8);

  bf16x8 onesf;
#pragma unroll
  for (int j = 0; j < 8; j++) onesf[j] = (short)0x3F80;

  f32x4 lsum = (f32x4)0.0f;
  f32x4 oacc[4];                               // O^T: row d=db*16+g*4+r, col q=lr
#pragma unroll
  for (int d = 0; d < 4; d++) oacc[d] = (f32x4)0.0f;

  const int strow = tid >> 3;
  const int stcolb = (tid & 7) * 16;
  const int swzb = stcolb ^ ((strow & 7) << 4);
  const u16* ksrc = k + (long)b * SEQ * LDQ + h * 64 + (swzb >> 1);
  const u16* vsrc = vt + ((long)(h * 64 + strow)) * (NB * SEQ) + (long)b * SEQ + (swzb >> 1);
  const int sc16 = stcolb >> 1;

  auto STAGE = [&](int buf, int kt) {
    const u16* kr = ksrc + (long)(kt * 64 + strow) * LDQ;
    gl_lds16(kr, &Ks[buf][strow][sc16]);
    gl_lds16(kr + (long)32 * LDQ, &Ks[buf][strow + 32][sc16]);
    const u16* vr = vsrc + kt * 64;
    gl_lds16(vr, &Vs[buf][strow][sc16]);
    gl_lds16(vr + 32 * (NB * SEQ), &Vs[buf][strow + 32][sc16]);
  };

  const int rs = (lr & 7) << 3;
  const int c0 = (g * 8) ^ rs;
  const int c1 = (32 + g * 8) ^ rs;

  const u64* mrow = mbitsT + (qr0 + lr);
  const int pswz = (lr & 7) << 2;              // Ps kp-swizzle (r7 layout)
  const int pb0 = (4 * g) ^ pswz;
  const int pb1 = (16 + 4 * g) ^ pswz;

  u64 mb_cur = mrow[0];
  STAGE(0, 0);
  for (int kt = 0; kt < NT; kt++) {
    const int cur = kt & 1;
    wait_vmcnt<0>();                           // own stage(t)+mask(t) drained
    __builtin_amdgcn_sched_barrier(0);
    __builtin_amdgcn_s_barrier();              // all compute(t-1) done; tile t valid
    u64 mb_new = 0;
    if (kt + 1 < NT) {
      mb_new = mrow[(long)(kt + 1) * SEQ];
      STAGE(cur ^ 1, kt + 1);                  // flies across this compute phase
    }

    f32x4 sf[4];
    __builtin_amdgcn_s_setprio(1);
#pragma unroll
    for (int n = 0; n < 4; n++) {
      bf16x8 kb0 = *(const bf16x8*)&Ks[cur][n * 16 + lr][c0];
      bf16x8 kb1 = *(const bf16x8*)&Ks[cur][n * 16 + lr][c1];
      sf[n] = __builtin_amdgcn_mfma_f32_16x16x32_bf16(kb0, qf0, (f32x4)0.0f, 0, 0, 0);
      sf[n] = __builtin_amdgcn_mfma_f32_16x16x32_bf16(kb1, qf1, sf[n], 0, 0, 0);
    }
    __builtin_amdgcn_s_setprio(0);
    u64 tsh = mb_cur >> (4 * g);
    u32 mlo = (u32)tsh, mhi = (u32)(tsh >> 32);
#pragma unroll
    for (int n = 0; n < 4; n++) {
      u32 w = (n < 2) ? mlo : mhi;
#pragma unroll
      for (int r = 0; r < 4; r++) {
        u32 bit = 1u << (16 * (n & 1) + r);
        sf[n][r] = (w & bit) ? sf[n][r] : NEGB;
      }
    }
    // P = exp2(s) via raw v_exp_f32 (1 instr); pack pairs via v_perm
#pragma unroll
    for (int n = 0; n < 4; n++) {
      union { float f; u32 i; } p0, p1, p2, p3;
      p0.f = hw_exp2(sf[n][0]); p1.f = hw_exp2(sf[n][1]);
      p2.f = hw_exp2(sf[n][2]); p3.f = hw_exp2(sf[n][3]);
      u32 w0 = __builtin_amdgcn_perm(p1.i, p0.i, 0x07060302u);
      u32 w1 = __builtin_amdgcn_perm(p3.i, p2.i, 0x07060302u);
      int widx = (8 * n + 2 * g) ^ pswz;
      *(u32x2*)&Ps32[wave][lr][widx] = (u32x2){w0, w1};
    }
    asm volatile("" ::: "memory");             // order Ps writes vs reads (same wave)
    bf16x8 pf0 = *(const bf16x8*)&Ps32[wave][lr][pb0];
    bf16x8 pf1 = *(const bf16x8*)&Ps32[wave][lr][pb1];
    __builtin_amdgcn_s_setprio(1);
    lsum = __builtin_amdgcn_mfma_f32_16x16x32_bf16(onesf, pf0, lsum, 0, 0, 0);
    lsum = __builtin_amdgcn_mfma_f32_16x16x32_bf16(onesf, pf1, lsum, 0, 0, 0);
#pragma unroll
    for (int db = 0; db < 4; db++) {
      bf16x8 v0 = *(const bf16x8*)&Vs[cur][db * 16 + lr][c0];
      bf16x8 v1 = *(const bf16x8*)&Vs[cur][db * 16 + lr][c1];
      oacc[db] = __builtin_amdgcn_mfma_f32_16x16x32_bf16(v0, pf0, oacc[db], 0, 0, 0);
      oacc[db] = __builtin_amdgcn_mfma_f32_16x16x32_bf16(v1, pf1, oacc[db], 0, 0, 0);
    }
    __builtin_amdgcn_s_setprio(0);
    mb_cur = mb_new;
  }
  float inv = 1.0f / lsum[0];
  long row = (long)b * SEQ + qr0 + lr;
#pragma unroll
  for (int db = 0; db < 4; db++) {
    u32 lo = ((u32)f2bf(oacc[db][1] * inv) << 16) | f2bf(oacc[db][0] * inv);
    u32 hi = ((u32)f2bf(oacc[db][3] * inv) << 16) | f2bf(oacc[db][2] * inv);
    *(u32x2*)(o_ + row * DM + h * 64 + db * 16 + g * 4) = (u32x2){lo, hi};
  }
}

extern "C" void kernel_launch(void* const* d_in, const int* in_sizes, int n_in,
                              void* d_out, int out_size, void* d_ws, size_t ws_size,
                              hipStream_t stream) {
  const float* x      = (const float*)d_in[0];
  const int*   mask   = (const int*)d_in[1];
  const float* wq     = (const float*)d_in[2];
  const float* bq     = (const float*)d_in[3];
  const float* wk     = (const float*)d_in[4];
  const float* bk     = (const float*)d_in[5];
  const float* wv     = (const float*)d_in[6];
  const float* bv     = (const float*)d_in[7];
  const float* wo     = (const float*)d_in[8];
  const float* bo     = (const float*)d_in[9];
  const float* w1     = (const float*)d_in[10];
  const float* b1     = (const float*)d_in[11];
  const float* w2     = (const float*)d_in[12];
  const float* b2     = (const float*)d_in[13];
  const float* alpha1 = (const float*)d_in[14];
  const float* beta1  = (const float*)d_in[15];
  const float* alpha2 = (const float*)d_in[16];
  const float* beta2  = (const float*)d_in[17];
  float* outf = (float*)d_out;

  // ---- workspace layout (~52.6 MiB) ----
  char* ws = (char*)d_ws;
  size_t off = 0;
  auto alloc = [&](size_t bytes) {
    void* p = ws + off;
    off += (bytes + 255) & ~(size_t)255;
    return p;
  };
  const size_t DD = (size_t)DM * DM * 2;
  const size_t DF = (size_t)DM * 3072 * 2;
  const size_t ROWS = (size_t)NB * SEQ;
  const size_t ACT = ROWS * DM * 2;

  u16* wqkvt = (u16*)alloc(3 * DD);
  u16* wot   = (u16*)alloc(DD);
  u16* w1t   = (u16*)alloc(DF);
  u16* w2t   = (u16*)alloc(DF);
  float* bqkv = (float*)alloc(3 * DM * 4);
  u64* mbitsT = (u64*)alloc((size_t)(SEQ / 64) * SEQ * 8);  // [32][2048] 512KB
  u16* h     = (u16*)alloc(ACT);
  u16* qkv   = (u16*)alloc(ROWS * 3 * DM * 2);
  u16* vtb   = (u16*)alloc(ACT);
  u16* ob    = (u16*)alloc(ACT);
  u16* fb = qkv;           // [4096][3072] bf16 over dead qkv|vtb
  u16* h2 = h;
  float* x1 = outf;        // d_out doubles as x1

  dim3 blk(256);
  prep_kernel<<<dim3(23305), blk, 0, stream>>>(wq, wk, wv, wo, w1, w2, bq, bk, bv,
                                               mask, wqkvt, wot, w1t, w2t, bqkv, mbitsT);

  ln_kernel<<<ROWS, blk, 0, stream>>>(x, alpha1, beta1, h);
  // fused QKV; V-tiles (n0 >= 1536) written transposed straight into vtb
  gemm_bt_kernel<128><<<dim3(576), blk, 0, stream>>>(
      h, wqkvt, bqkv, nullptr, qkv, nullptr, vtb, 2 * DM, 4096, 3 * DM, 768, 768, 0, 18, 0);
  attn_kernel<<<dim3(32 * NH * NB), blk, 0, stream>>>(qkv, vtb, mbitsT, ob);
  gemm_bt_kernel<64><<<dim3(384), blk, 0, stream>>>(
      ob, wot, bo, x, nullptr, x1, nullptr, 0, 4096, 768, 768, 768, 0, 12, 0);
  ln_kernel<<<ROWS, blk, 0, stream>>>(x1, alpha2, beta2, h2);
  gemm_bt_kernel<128><<<dim3(768), blk, 0, stream>>>(
      h2, w1t, b1, nullptr, fb, nullptr, nullptr, 0, 4096, 3072, 768, 768, 1, 24, 0);
  // FFN2 split-K x2, BN=128 (nx=6): 384 blocks, 48 iters of 16 MFMA
  gemm_bt_kernel<128><<<dim3(384), blk, 0, stream>>>(
      fb, w2t, b2, nullptr, nullptr, outf, nullptr, 0, 4096, 768, 1536, 3072, 0, 6, 192);
}